// Round 10
// baseline (1375.077 us; speedup 1.0000x reference)
//
#include <hip/hip_runtime.h>

#define NB 128
#define NS 256
#define NI 64
#define NH 128
#define NL 64
#define NG 384  // 3*NH

typedef _Float16 f16;
typedef __attribute__((ext_vector_type(2))) _Float16 f16x2;

__device__ __forceinline__ float fast_tanh(float x) {
    float e = __expf(2.0f * x);
    return 1.0f - 2.0f / (e + 1.0f);
}
__device__ __forceinline__ float fast_sig(float x) {
    return 1.0f / (1.0f + __expf(-x));
}
__device__ __forceinline__ float red1(float a) {  // epilogue pair-reduce
    int ai = __builtin_bit_cast(int, a);
    int bi = __builtin_amdgcn_update_dpp(0, ai, 0xB1, 0xF, 0xF, true);
    return a + __builtin_bit_cast(float, bi);
}
__device__ __forceinline__ float fdot2(f16x2 a, f16x2 b, float c) {
#if __has_builtin(__builtin_amdgcn_fdot2)
    return __builtin_amdgcn_fdot2(a, b, c, false);
#else
    return c + (float)a.x * (float)b.x + (float)a.y * (float)b.y;
#endif
}
__device__ __forceinline__ f16x2 bcu(int u) {
    return __builtin_bit_cast(f16x2, u);
}
__device__ __forceinline__ int pack2h(float x, float y) {
    f16x2 v; v.x = (f16)x; v.y = (f16)y;
    return __builtin_bit_cast(int, v);
}
// LDS-only workgroup barrier (no vmcnt drain: global prefetch stays in flight)
__device__ __forceinline__ void sync_lds() {
    asm volatile("s_waitcnt lgkmcnt(0)" ::: "memory");
    __builtin_amdgcn_s_barrier();
    asm volatile("" ::: "memory");
}

// ---- f16 weight tables (pre-rounded once by prep_kernel) ----
__device__ __align__(16) f16 g_W1h[NH * NH];
__device__ __align__(16) f16 g_W2h[NH * NH];
__device__ __align__(16) f16 g_W12h[NH * NH];
__device__ __align__(16) f16 g_Whhh[3 * NH * NH];
__device__ __align__(16) f16 g_Whh2h[3 * NH * NH];
__device__ float g_w1b2[NH];
__device__ float g_whhb2[3 * NH];
__device__ float g_gxfb[(size_t)NS * NB * NG];  // gx fallback if ws too small

// ---------------------------------------------------------------------------
// GX precompute: gx[s][b][j] = b_ih[j] + sum_c x[b][s][c] * W_ih[j][c]
// ---------------------------------------------------------------------------
__global__ __launch_bounds__(384)
void gx_kernel(const float* __restrict__ x, const float* __restrict__ W_ih,
               const float* __restrict__ b_ih, float* __restrict__ gx)
{
    const int s = blockIdx.x;
    const int j = threadIdx.x;
    __shared__ __align__(16) float xs[NB * NI];
    for (int idx = j; idx < NB * NI; idx += 384) {
        int bb = idx >> 6, cc = idx & 63;
        xs[idx] = x[(bb * NS + s) * NI + cc];
    }
    float w[64];
#pragma unroll
    for (int c = 0; c < 64; c += 4)
        *(float4*)&w[c] = *(const float4*)&W_ih[j * NI + c];
    const float bj = b_ih[j];
    __syncthreads();
    for (int bb = 0; bb < NB; bb++) {
        const float* xr = xs + bb * NI;
        float a0 = 0.f, a1 = 0.f, a2 = 0.f, a3 = 0.f;
#pragma unroll
        for (int c = 0; c < 64; c += 4) {
            a0 = fmaf(w[c + 0], xr[c + 0], a0);
            a1 = fmaf(w[c + 1], xr[c + 1], a1);
            a2 = fmaf(w[c + 2], xr[c + 2], a2);
            a3 = fmaf(w[c + 3], xr[c + 3], a3);
        }
        gx[((size_t)s * NB + bb) * NG + j] = ((a0 + a1) + (a2 + a3)) + bj;
    }
}

// ---------------------------------------------------------------------------
// Setup (fp32 math, then round to f16): W12=W1@W2, Whh2=Whh@W2, W1b2, Whhb2,
// plus f16 copies of W1, W2, Whh.
// ---------------------------------------------------------------------------
__global__ __launch_bounds__(128)
void prep_kernel(const float* __restrict__ W1, const float* __restrict__ Whh,
                 const float* __restrict__ W2, const float* __restrict__ b2)
{
    const int i = blockIdx.x;   // 0..511
    const int j = threadIdx.x;  // 0..127
    __shared__ float rowA[NH];
    __shared__ float red[NH];
    const float* src = (i < NH) ? (W1 + i * NH) : (Whh + (size_t)(i - NH) * NH);
    rowA[j] = src[j];
    __syncthreads();
    float acc = 0.f;
    for (int k = 0; k < NH; k++) acc = fmaf(rowA[k], W2[k * NH + j], acc);
    if (i < NH) {
        g_W12h[i * NH + j] = (f16)acc;
        g_W1h[i * NH + j]  = (f16)rowA[j];
        g_W2h[i * NH + j]  = (f16)W2[i * NH + j];
    } else {
        g_Whh2h[(size_t)(i - NH) * NH + j] = (f16)acc;
        g_Whhh[(size_t)(i - NH) * NH + j]  = (f16)rowA[j];
    }
    red[j] = rowA[j] * b2[j];
    __syncthreads();
    for (int off = 64; off > 0; off >>= 1) {
        if (j < off) red[j] += red[j + off];
        __syncthreads();
    }
    if (j == 0) {
        if (i < NH) g_w1b2[i] = red[0];
        else        g_whhb2[i - NH] = red[0];
    }
}

// ---------------------------------------------------------------------------
// bpermute-broadcast matvec: PK = per-lane u32 pack (elements 2L,2L+1).
// ds_bpermute(4k, PK) broadcasts lane k's pack to all lanes (register
// crossbar — no LDS memory, no barrier, lgkmcnt-pipelined).
// Weights: int[64] per row, literal indices only.
// ---------------------------------------------------------------------------
#define BDOT(WA, WB, PK, O0, O1)                                               \
    {                                                                          \
        float a0_ = 0.f, a1_ = 0.f, b0_ = 0.f, b1_ = 0.f;                      \
        _Pragma("unroll") for (int k = 0; k < 64; k += 2)                      \
        {                                                                      \
            int v0_ = __builtin_amdgcn_ds_bpermute(4 * k, (PK));               \
            int v1_ = __builtin_amdgcn_ds_bpermute(4 * k + 4, (PK));           \
            a0_ = fdot2(bcu(WA[k]), bcu(v0_), a0_);                            \
            b0_ = fdot2(bcu(WB[k]), bcu(v0_), b0_);                            \
            a1_ = fdot2(bcu(WA[k + 1]), bcu(v1_), a1_);                        \
            b1_ = fdot2(bcu(WB[k + 1]), bcu(v1_), b1_);                        \
        }                                                                      \
        O0 = a0_ + a1_;                                                        \
        O1 = b0_ + b1_;                                                        \
    }

// load one full f16 row (128 = 256B) into int[64]
#define LOADROW(DST, BASE)                                                     \
    {                                                                          \
        const uint4* p_ = (const uint4*)(BASE);                                \
        _Pragma("unroll") for (int j_ = 0; j_ < 16; j_++)                      \
        {                                                                      \
            uint4 v_ = p_[j_];                                                 \
            DST[4 * j_ + 0] = v_.x; DST[4 * j_ + 1] = v_.y;                    \
            DST[4 * j_ + 2] = v_.z; DST[4 * j_ + 3] = v_.w;                    \
        }                                                                      \
    }

#define PIN2(A, B)                                                             \
    _Pragma("unroll") for (int i_ = 0; i_ < 64; i_++)                          \
    { asm volatile("" : "+v"(A[i_]), "+v"(B[i_])); }

// ---------------------------------------------------------------------------
// Main recurrence: 1 WG / batch element, 512 threads = 8 waves (2/SIMD).
// w0: st1 (W1 from swizzled LDS) + barrier-free bpermute chain (W12 regs).
// w1: W2 -> hB; owns h; GRU. w2-4: Whh_g·h (chain window). w5-7: Whh2_g·Spp.
// 3 barriers/step: B_h -> B2 (Spp+GA) -> B_fin (GS).
// ---------------------------------------------------------------------------
__global__ __launch_bounds__(512, 2)
void rnn_kernel(const float* __restrict__ times, const float* __restrict__ b_hh,
                const float* __restrict__ b1, const float* __restrict__ b2,
                const float* __restrict__ W_mean, const float* __restrict__ b_mean,
                const float* __restrict__ W_logvar, const float* __restrict__ b_logvar,
                const float* __restrict__ gx,
                float* __restrict__ out)
{
    const int b = blockIdx.x;
    const int t = threadIdx.x;   // 0..511
    const int w = t >> 6;        // wave 0..7
    const int L = t & 63;        // lane
    const int r0 = 2 * L, r1 = 2 * L + 1;
    const int key = L & 7;       // sW1 swizzle key (= (r0>>1)&7 = (r1>>1)&7)

    __shared__ float shT[NS];
    __shared__ int shHpk[64];        // h pack (f16x2 rows 2L,2L+1)
    __shared__ int shSpp[64];        // (S+S2) pack
    __shared__ float2 shGA[3][64];   // Whh_g · h
    __shared__ float2 shGS[3][64];   // Whh2_g · Spp
    __shared__ __align__(16) unsigned int sW1[NH * 64];  // 32KB swizzled W1
    __shared__ __align__(16) float shHfl[NH];

    // stage sW1 (chunk j of row r stored at j ^ ((r>>1)&7)) — conflict-free reads
    for (int idx = t; idx < NH * 16; idx += 512) {
        const int r = idx >> 4, j = idx & 15;
        uint4 v = ((const uint4*)g_W1h)[idx];
        ((uint4*)sW1)[(r << 4) | (j ^ ((r >> 1) & 7))] = v;
    }
    for (int i = t; i < NS; i += 512) shT[i] = times[i];
    if (t < 64) shHpk[t] = 0;
    __syncthreads();

    // ---- per-wave persistent weight rows (<=128 u32) ----
    int wa[64], wb[64];
    if (w == 0) {
        LOADROW(wa, g_W12h + r0 * NH);
        LOADROW(wb, g_W12h + r1 * NH);
    } else if (w == 1) {
        LOADROW(wa, g_W2h + r0 * NH);
        LOADROW(wb, g_W2h + r1 * NH);
    } else if (w <= 4) {
        const int g = w - 2;
        LOADROW(wa, g_Whhh + (size_t)(g * NH + r0) * NH);
        LOADROW(wb, g_Whhh + (size_t)(g * NH + r1) * NH);
    } else {
        const int g = w - 5;
        LOADROW(wa, g_Whh2h + (size_t)(g * NH + r0) * NH);
        LOADROW(wb, g_Whh2h + (size_t)(g * NH + r1) * NH);
    }

    const float b1r0 = b1[r0], b1r1 = b1[r1];
    const float w1b20 = g_w1b2[r0], w1b21 = g_w1b2[r1];
    const float b20 = b2[r0], b21 = b2[r1];
    // w1 GRU scalars
    float bhr0 = 0, bhr1 = 0, bhz0 = 0, bhz1 = 0, bhn0 = 0, bhn1 = 0;
    float sbr0 = 0, sbr1 = 0, sbz0 = 0, sbz1 = 0, sbn0 = 0, sbn1 = 0;
    if (w == 1) {
        bhr0 = b_hh[r0]; bhr1 = b_hh[r1];
        bhz0 = b_hh[NH + r0]; bhz1 = b_hh[NH + r1];
        bhn0 = b_hh[2 * NH + r0]; bhn1 = b_hh[2 * NH + r1];
        sbr0 = g_whhb2[r0]; sbr1 = g_whhb2[r1];
        sbz0 = g_whhb2[NH + r0]; sbz1 = g_whhb2[NH + r1];
        sbn0 = g_whhb2[2 * NH + r0]; sbn1 = g_whhb2[2 * NH + r1];
    }

    float h0 = 0.f, h1 = 0.f;               // live in w1
    float2 gxr, gxz, gxn;                   // w1 gx prefetch

    for (int si = 0; si < NS; ++si) {
        const int seq = NS - 1 - si;
        const float dt = (si == 0) ? 0.f : (shT[seq] - shT[seq + 1]);
        const float dts = 0.5f * dt;   // substep dt (N_SUB=2)
        const float a2c = 0.5f * dts;
        const float a6 = dts * (1.f / 6.f);

        sync_lds();  // ===== B_h: h pack from previous iteration visible =====

        if (w == 0) {
            PIN2(wa, wb);
            const int hpk = shHpk[L];
            // ---- st1: z1a = W1 h + b1 (W1 streamed from swizzled LDS) ----
            float z1a0, z1a1;
            {
                float a0_ = 0.f, a1_ = 0.f, c0_ = 0.f, c1_ = 0.f;
#pragma unroll
                for (int c = 0; c < 8; c++) {
                    uint4 va  = ((const uint4*)sW1)[(r0 << 4) | ((2 * c) ^ key)];
                    uint4 va2 = ((const uint4*)sW1)[(r0 << 4) | ((2 * c + 1) ^ key)];
                    uint4 vb  = ((const uint4*)sW1)[(r1 << 4) | ((2 * c) ^ key)];
                    uint4 vb2 = ((const uint4*)sW1)[(r1 << 4) | ((2 * c + 1) ^ key)];
                    int p0 = __builtin_amdgcn_ds_bpermute(4 * (8 * c + 0), hpk);
                    int p1 = __builtin_amdgcn_ds_bpermute(4 * (8 * c + 1), hpk);
                    int p2 = __builtin_amdgcn_ds_bpermute(4 * (8 * c + 2), hpk);
                    int p3 = __builtin_amdgcn_ds_bpermute(4 * (8 * c + 3), hpk);
                    int p4 = __builtin_amdgcn_ds_bpermute(4 * (8 * c + 4), hpk);
                    int p5 = __builtin_amdgcn_ds_bpermute(4 * (8 * c + 5), hpk);
                    int p6 = __builtin_amdgcn_ds_bpermute(4 * (8 * c + 6), hpk);
                    int p7 = __builtin_amdgcn_ds_bpermute(4 * (8 * c + 7), hpk);
                    a0_ = fdot2(bcu(va.x),  bcu(p0), a0_);
                    a1_ = fdot2(bcu(va.y),  bcu(p1), a1_);
                    a0_ = fdot2(bcu(va.z),  bcu(p2), a0_);
                    a1_ = fdot2(bcu(va.w),  bcu(p3), a1_);
                    a0_ = fdot2(bcu(va2.x), bcu(p4), a0_);
                    a1_ = fdot2(bcu(va2.y), bcu(p5), a1_);
                    a0_ = fdot2(bcu(va2.z), bcu(p6), a0_);
                    a1_ = fdot2(bcu(va2.w), bcu(p7), a1_);
                    c0_ = fdot2(bcu(vb.x),  bcu(p0), c0_);
                    c1_ = fdot2(bcu(vb.y),  bcu(p1), c1_);
                    c0_ = fdot2(bcu(vb.z),  bcu(p2), c0_);
                    c1_ = fdot2(bcu(vb.w),  bcu(p3), c1_);
                    c0_ = fdot2(bcu(vb2.x), bcu(p4), c0_);
                    c1_ = fdot2(bcu(vb2.y), bcu(p5), c1_);
                    c0_ = fdot2(bcu(vb2.z), bcu(p6), c0_);
                    c1_ = fdot2(bcu(vb2.w), bcu(p7), c1_);
                }
                z1a0 = a0_ + a1_ + b1r0;
                z1a1 = c0_ + c1_ + b1r1;
            }
            // ---- barrier-free chain st2..st8 ----
            float u0 = fast_tanh(z1a0), u1 = fast_tanh(z1a1);
            float S0 = u0, S1 = u1;
            int upk = pack2h(u0, u1);
            float m0, m1;
            // st2
            BDOT(wa, wb, upk, m0, m1);
            u0 = fast_tanh(z1a0 + a2c * (m0 + w1b20));
            u1 = fast_tanh(z1a1 + a2c * (m1 + w1b21));
            S0 += 2.f * u0; S1 += 2.f * u1;
            upk = pack2h(u0, u1);
            // st3
            BDOT(wa, wb, upk, m0, m1);
            u0 = fast_tanh(z1a0 + a2c * (m0 + w1b20));
            u1 = fast_tanh(z1a1 + a2c * (m1 + w1b21));
            S0 += 2.f * u0; S1 += 2.f * u1;
            upk = pack2h(u0, u1);
            // st4 (k4 uses full dts)
            BDOT(wa, wb, upk, m0, m1);
            u0 = fast_tanh(z1a0 + dts * (m0 + w1b20));
            u1 = fast_tanh(z1a1 + dts * (m1 + w1b21));
            S0 += u0; S1 += u1;
            // st5: z1b = z1a + a6*W12*S + dts*w1b2
            int Spk = pack2h(S0, S1);
            BDOT(wa, wb, Spk, m0, m1);
            const float zb0 = z1a0 + a6 * m0 + dts * w1b20;
            const float zb1 = z1a1 + a6 * m1 + dts * w1b21;
            u0 = fast_tanh(zb0); u1 = fast_tanh(zb1);
            float S20 = u0, S21 = u1;
            upk = pack2h(u0, u1);
            // st6
            BDOT(wa, wb, upk, m0, m1);
            u0 = fast_tanh(zb0 + a2c * (m0 + w1b20));
            u1 = fast_tanh(zb1 + a2c * (m1 + w1b21));
            S20 += 2.f * u0; S21 += 2.f * u1;
            upk = pack2h(u0, u1);
            // st7
            BDOT(wa, wb, upk, m0, m1);
            u0 = fast_tanh(zb0 + a2c * (m0 + w1b20));
            u1 = fast_tanh(zb1 + a2c * (m1 + w1b21));
            S20 += 2.f * u0; S21 += 2.f * u1;
            upk = pack2h(u0, u1);
            // st8
            BDOT(wa, wb, upk, m0, m1);
            u0 = fast_tanh(zb0 + dts * (m0 + w1b20));
            u1 = fast_tanh(zb1 + dts * (m1 + w1b21));
            S20 += u0; S21 += u1;
            shSpp[L] = pack2h(S0 + S20, S1 + S21);
        } else if (w >= 2 && w <= 4) {
            // gates part 1: Whh_g · h (huge window, off critical path)
            const int hpk = shHpk[L];
            float g0, g1;
            BDOT(wa, wb, hpk, g0, g1);
            shGA[w - 2][L] = make_float2(g0, g1);
        } else if (w == 1) {
            // issue gx loads (consumed after B_fin; vmcnt not drained by sync_lds)
            const float* gp = gx + ((size_t)seq * NB + b) * NG;
            gxr = *(const float2*)(gp + r0);
            gxz = *(const float2*)(gp + NH + r0);
            gxn = *(const float2*)(gp + 2 * NH + r0);
        }

        sync_lds();  // ===== B2: Spp + GA visible =====

        float hB0 = 0.f, hB1 = 0.f;
        if (w == 1) {
            const int spk = shSpp[L];
            float q0, q1;
            BDOT(wa, wb, spk, q0, q1);
            hB0 = h0 + a6 * q0 + 2.f * dts * b20;
            hB1 = h1 + a6 * q1 + 2.f * dts * b21;
        } else if (w >= 5) {
            const int spk = shSpp[L];
            float s0, s1;
            BDOT(wa, wb, spk, s0, s1);
            shGS[w - 5][L] = make_float2(s0, s1);
        }

        sync_lds();  // ===== B_fin: GS visible =====

        if (w == 1) {
            const float tdts = 2.f * dts;
            float2 GAr = shGA[0][L], GAz = shGA[1][L], GAn = shGA[2][L];
            float2 GSr = shGS[0][L], GSz = shGS[1][L], GSn = shGS[2][L];
            const float ghr0 = GAr.x + a6 * GSr.x + tdts * sbr0 + bhr0;
            const float ghr1 = GAr.y + a6 * GSr.y + tdts * sbr1 + bhr1;
            const float ghz0 = GAz.x + a6 * GSz.x + tdts * sbz0 + bhz0;
            const float ghz1 = GAz.y + a6 * GSz.y + tdts * sbz1 + bhz1;
            const float ghn0 = GAn.x + a6 * GSn.x + tdts * sbn0 + bhn0;
            const float ghn1 = GAn.y + a6 * GSn.y + tdts * sbn1 + bhn1;
            const float rr0 = fast_sig(gxr.x + ghr0);
            const float rr1 = fast_sig(gxr.y + ghr1);
            const float zz0 = fast_sig(gxz.x + ghz0);
            const float zz1 = fast_sig(gxz.y + ghz1);
            const float nn0 = fast_tanh(gxn.x + rr0 * ghn0);
            const float nn1 = fast_tanh(gxn.y + rr1 * ghn1);
            h0 = (1.f - zz0) * nn0 + zz0 * hB0;
            h1 = (1.f - zz1) * nn1 + zz1 * hB1;
            shHpk[L] = pack2h(h0, h1);   // visible at next iteration's B_h
        }
    }

    // ---- epilogue: heads from final fp32 h ----
    if (w == 1) { shHfl[r0] = h0; shHfl[r1] = h1; }
    __syncthreads();
    if (t < 256) {
        const int rr = t >> 1;
        const int pp = t & 1;
        const int sel = rr >> 6;
        const int l = rr & 63;
        const float* Wf = sel ? W_logvar : W_mean;
        const int hc0 = 64 * pp;
        float a0 = 0.f, a1 = 0.f;
#pragma unroll
        for (int jj = 0; jj < 16; jj++) {
            float4 w4 = *(const float4*)&Wf[l * NH + hc0 + 4 * jj];
            float4 h4 = *(const float4*)(shHfl + hc0 + 4 * jj);
            a0 = fmaf(w4.x, h4.x, a0);
            a1 = fmaf(w4.y, h4.y, a1);
            a0 = fmaf(w4.z, h4.z, a0);
            a1 = fmaf(w4.w, h4.w, a1);
        }
        float acc = red1(a0 + a1);
        if (pp == 0) {
            const float bias = sel ? b_logvar[l] : b_mean[l];
            out[sel * (NB * NL) + b * NL + l] = acc + bias;
        }
    }
}

extern "C" void kernel_launch(void* const* d_in, const int* in_sizes, int n_in,
                              void* d_out, int out_size, void* d_ws, size_t ws_size,
                              hipStream_t stream)
{
    const float* x        = (const float*)d_in[0];
    const float* times    = (const float*)d_in[1];
    const float* W_ih     = (const float*)d_in[2];
    const float* W_hh     = (const float*)d_in[3];
    const float* b_ih     = (const float*)d_in[4];
    const float* b_hh     = (const float*)d_in[5];
    const float* W1       = (const float*)d_in[6];
    const float* b1       = (const float*)d_in[7];
    const float* W2       = (const float*)d_in[8];
    const float* b2       = (const float*)d_in[9];
    const float* W_mean   = (const float*)d_in[10];
    const float* b_mean   = (const float*)d_in[11];
    const float* W_logvar = (const float*)d_in[12];
    const float* b_logvar = (const float*)d_in[13];
    float* out = (float*)d_out;

    const size_t need = (size_t)NS * NB * NG * sizeof(float);  // ~50.3 MB
    float* gxbuf;
    if (d_ws != nullptr && ws_size >= need) {
        gxbuf = (float*)d_ws;
    } else {
        void* p = nullptr;
        hipGetSymbolAddress(&p, HIP_SYMBOL(g_gxfb));
        gxbuf = (float*)p;
    }

    gx_kernel<<<NS, 384, 0, stream>>>(x, W_ih, b_ih, gxbuf);
    prep_kernel<<<512, 128, 0, stream>>>(W1, W_hh, W2, b2);
    rnn_kernel<<<NB, 512, 0, stream>>>(times, b_hh, b1, b2,
                                       W_mean, b_mean, W_logvar, b_logvar,
                                       gxbuf, out);
}